// Round 7
// baseline (911.602 us; speedup 1.0000x reference)
//
#include <hip/hip_runtime.h>
#include <hip/hip_bf16.h>
#include <stdint.h>

#define B_SZ 64
#define L_SZ 2048
#define V_SZ 1024
#define H_SZ 256
#define HALF_SZ 128
#define NTOK (B_SZ * L_SZ)   // 131072
#define CH 16384             // token chunk (8 chunks)

typedef unsigned short ushort_t;
typedef __attribute__((ext_vector_type(8))) short bf16x8;
typedef __attribute__((ext_vector_type(4))) float f32x4;

__device__ __forceinline__ ushort_t f2bf(float f) {
    __hip_bfloat16 h = __float2bfloat16(f);
    return *reinterpret_cast<ushort_t*>(&h);
}

// ---------------------------------------------------------------------------
// f32 -> bf16 convert (same layout). n multiple of 1024.
// ---------------------------------------------------------------------------
__global__ __launch_bounds__(256) void cvt_bf16_k(
    const float* __restrict__ src, ushort_t* __restrict__ dst, int n)
{
    int i = (blockIdx.x * 256 + threadIdx.x) * 4;
    if (i >= n) return;
    float4 v = *(const float4*)(src + i);
    uint2 pk;
    pk.x = (uint32_t)f2bf(v.x) | ((uint32_t)f2bf(v.y) << 16);
    pk.y = (uint32_t)f2bf(v.z) | ((uint32_t)f2bf(v.w) << 16);
    *(uint2*)(dst + i) = pk;
}

// ---------------------------------------------------------------------------
// dst[n*K + k] = bf16(src[k*N + n])  — weight transpose + convert (tiny).
// ---------------------------------------------------------------------------
__global__ __launch_bounds__(256) void transpose_cvt_k(
    const float* __restrict__ src, ushort_t* __restrict__ dst, int K, int N)
{
    int idx = blockIdx.x * 256 + threadIdx.x;
    if (idx >= K * N) return;
    int n = idx / K;
    int k = idx - n * K;
    dst[idx] = f2bf(src[(size_t)k * N + n]);
}

// ---------------------------------------------------------------------------
// bf16 MFMA GEMM: C[128 x 128-tile] = A[M][K] @ BT[N][K]^T, 256 thr / 4 waves.
// BK=64, LDS XOR-swizzled (chunk ^= row&7) for conflict-free ds_read_b128.
// MODE 1: A row = embed_bf[seq[m]]; C = relu(acc+bias) -> bf16
// MODE 2: A = t1 bf16;  C = acc + bias + embed_f32[seq[m]][n] -> f32
// MODE 3: A = h bf16;   C = acc + bias -> f32
// ---------------------------------------------------------------------------
template <int MODE, int K, int N>
__global__ __launch_bounds__(256) void gemm_mfma(
    const ushort_t* __restrict__ A, const ushort_t* __restrict__ BT,
    const float* __restrict__ bias, void* __restrict__ Cp,
    const int* __restrict__ seq, const float* __restrict__ embed)
{
    __shared__ __align__(16) ushort_t Asm[128 * 64];
    __shared__ __align__(16) ushort_t Bsm[128 * 64];

    const int tid = threadIdx.x;
    const int m0 = blockIdx.x * 128;
    const int n0 = blockIdx.y * 128;
    const int w = tid >> 6;
    const int l = tid & 63;
    const int wr = w >> 1;   // wave tile row (0..1)
    const int wc = w & 1;    // wave tile col (0..1)

    // staging row base pointers (rows fixed across K-loop)
    const ushort_t* arow[4];
    const ushort_t* brow[4];
#pragma unroll
    for (int i = 0; i < 4; ++i) {
        const int flat = i * 256 + tid;       // 0..1023
        const int r = flat >> 3;              // 0..127
        const int gr = (MODE == 1) ? seq[m0 + r] : (m0 + r);
        arow[i] = A + (size_t)gr * K;
        brow[i] = BT + (size_t)(n0 + r) * K;
    }

    f32x4 acc[4][4];
#pragma unroll
    for (int mi = 0; mi < 4; ++mi)
#pragma unroll
        for (int nj = 0; nj < 4; ++nj)
            acc[mi][nj] = (f32x4){0.f, 0.f, 0.f, 0.f};

    for (int kt = 0; kt < K / 64; ++kt) {
#pragma unroll
        for (int i = 0; i < 4; ++i) {
            const int flat = i * 256 + tid;
            const int r = flat >> 3;          // tile row
            const int c = flat & 7;           // 16B chunk within 128B row
            const int cs = c ^ (r & 7);       // swizzled chunk
            uint4 av = *(const uint4*)(arow[i] + kt * 64 + c * 8);
            *(uint4*)&Asm[r * 64 + cs * 8] = av;
            uint4 bv = *(const uint4*)(brow[i] + kt * 64 + c * 8);
            *(uint4*)&Bsm[r * 64 + cs * 8] = bv;
        }
        __syncthreads();
#pragma unroll
        for (int kh = 0; kh < 2; ++kh) {
            bf16x8 af[4], bfr[4];
#pragma unroll
            for (int mi = 0; mi < 4; ++mi) {
                const int r = wr * 64 + mi * 16 + (l & 15);
                const int c = (kh * 4 + (l >> 4)) ^ (r & 7);
                af[mi] = *(const bf16x8*)&Asm[r * 64 + c * 8];
            }
#pragma unroll
            for (int nj = 0; nj < 4; ++nj) {
                const int r = wc * 64 + nj * 16 + (l & 15);
                const int c = (kh * 4 + (l >> 4)) ^ (r & 7);
                bfr[nj] = *(const bf16x8*)&Bsm[r * 64 + c * 8];
            }
#pragma unroll
            for (int mi = 0; mi < 4; ++mi)
#pragma unroll
                for (int nj = 0; nj < 4; ++nj)
                    acc[mi][nj] = __builtin_amdgcn_mfma_f32_16x16x32_bf16(
                        af[mi], bfr[nj], acc[mi][nj], 0, 0, 0);
        }
        __syncthreads();
    }

    // epilogue: C/D layout col = lane&15, row = (lane>>4)*4 + reg
    const int cl = l & 15;
    const int rg = l >> 4;
    float bv[4];
#pragma unroll
    for (int nj = 0; nj < 4; ++nj)
        bv[nj] = bias[n0 + wc * 64 + nj * 16 + cl];

#pragma unroll
    for (int mi = 0; mi < 4; ++mi) {
#pragma unroll
        for (int i = 0; i < 4; ++i) {
            const int row = m0 + wr * 64 + mi * 16 + rg * 4 + i;  // chunk-local
            const float* erow = (MODE == 2)
                ? (embed + (size_t)seq[row] * H_SZ) : nullptr;
#pragma unroll
            for (int nj = 0; nj < 4; ++nj) {
                const int gn = n0 + wc * 64 + nj * 16 + cl;
                float v = acc[mi][nj][i] + bv[nj];
                if (MODE == 1) {
                    v = fmaxf(v, 0.f);
                    ((ushort_t*)Cp)[(size_t)row * N + gn] = f2bf(v);
                } else if (MODE == 2) {
                    ((float*)Cp)[(size_t)row * N + gn] = v + erow[gn];
                } else {
                    ((float*)Cp)[(size_t)row * N + gn] = v;
                }
            }
        }
    }
}

// ---------------------------------------------------------------------------
// LayerNorm over H=256: one wave per token, 4 tokens per block (chunk-local).
// ---------------------------------------------------------------------------
__global__ __launch_bounds__(256) void ln_k(
    const float* __restrict__ x, const float* __restrict__ g,
    const float* __restrict__ bt, ushort_t* __restrict__ h)
{
    const int token = blockIdx.x * 4 + (threadIdx.x >> 6);
    const int lane = threadIdx.x & 63;
    const float* xr = x + (size_t)token * H_SZ + lane * 4;
    const float4 v = *(const float4*)xr;
    float s = v.x + v.y + v.z + v.w;
    float sq = v.x * v.x + v.y * v.y + v.z * v.z + v.w * v.w;
#pragma unroll
    for (int m = 1; m < 64; m <<= 1) {
        s += __shfl_xor(s, m);
        sq += __shfl_xor(sq, m);
    }
    const float mu = s * (1.f / H_SZ);
    const float var = sq * (1.f / H_SZ) - mu * mu;
    const float rs = rsqrtf(var + 1e-5f);
    const int idx = lane * 4;
    const float4 gg = *(const float4*)(g + idx);
    const float4 bb = *(const float4*)(bt + idx);
    ushort_t o0 = f2bf((v.x - mu) * rs * gg.x + bb.x);
    ushort_t o1 = f2bf((v.y - mu) * rs * gg.y + bb.y);
    ushort_t o2 = f2bf((v.z - mu) * rs * gg.z + bb.z);
    ushort_t o3 = f2bf((v.w - mu) * rs * gg.w + bb.w);
    uint2 pk;
    pk.x = (uint32_t)o0 | ((uint32_t)o1 << 16);
    pk.y = (uint32_t)o2 | ((uint32_t)o3 << 16);
    *(uint2*)(h + (size_t)token * H_SZ + idx) = pk;
}

// ---------------------------------------------------------------------------
// gram8_k: per (pair, 8-token block) precompute the 8x8 block Gram and the
// solve coefficients. Output record (48 floats):
//   [0..27]  L[i][j] = alpha_j * (k_i . k_j)  (i>j, idx = i(i-1)/2+j)
//   [28..35] alpha_i = beta_i / (|k_i|^2 + 1e-6)
//   [36..43] beta_i  (0 for token L-1; 1 for s-half; (t+1)/L for e-half)
// Token i=0 in a block is the HIGHEST token (t = 8*bi+7), matching the
// descending-t order of the backward scan. Fully parallel: 32768 waves.
// ---------------------------------------------------------------------------
__global__ __launch_bounds__(256) void gram8_k(
    const float* __restrict__ proj, float* __restrict__ g8)
{
    const int pair = blockIdx.y;               // 0..127
    const int b = pair >> 1;
    const int half = pair & 1;
    const int bi = blockIdx.x * 4 + (threadIdx.x >> 6);   // 0..255
    const int l = threadIdx.x & 63;

    const float* kbase = proj + (size_t)b * L_SZ * H_SZ + half * HALF_SZ;

    float2 kk[8];
#pragma unroll
    for (int i = 0; i < 8; ++i) {
        const int tok = bi * 8 + 7 - i;
        kk[i] = *(const float2*)(kbase + (size_t)tok * H_SZ + 2 * l);
    }

    float r[36];
#pragma unroll
    for (int i = 0; i < 8; ++i)
        r[i] = kk[i].x * kk[i].x + kk[i].y * kk[i].y;
#pragma unroll
    for (int i = 1; i < 8; ++i)
#pragma unroll
        for (int j = 0; j < i; ++j)
            r[8 + i * (i - 1) / 2 + j] = kk[i].x * kk[j].x + kk[i].y * kk[j].y;

#pragma unroll
    for (int m = 1; m < 64; m <<= 1)
#pragma unroll
        for (int t = 0; t < 36; ++t)
            r[t] += __shfl_xor(r[t], m);

    const float invL = 1.0f / (float)L_SZ;
    float al[8], be[8];
#pragma unroll
    for (int i = 0; i < 8; ++i) {
        const int tok = bi * 8 + 7 - i;
        const float bet = (tok == L_SZ - 1)
            ? 0.f : (half ? (float)(tok + 1) * invL : 1.0f);
        be[i] = bet;
        al[i] = bet / (r[i] + 1e-6f);
    }

    if (l == 0) {
        float* out = g8 + ((size_t)pair * 256 + bi) * 48;
#pragma unroll
        for (int i = 1; i < 8; ++i)
#pragma unroll
            for (int j = 0; j < i; ++j)
                out[i * (i - 1) / 2 + j] = al[j] * r[8 + i * (i - 1) / 2 + j];
#pragma unroll
        for (int i = 0; i < 8; ++i) {
            out[28 + i] = al[i];
            out[36 + i] = be[i];
        }
    }
}

// ---------------------------------------------------------------------------
// scan_bw8_k: backward vector scan with W=8 windows and precomputed Grams.
//   per 8-step block (descending t):
//     a_i = k_i . v               (8 butterflies, only chain that needs v)
//     d_i = a_i - sum_{j<i} L[i][j] d_j        (scalar, uniform)
//     v  -= sum_i (alpha_i d_i) k_i ;  c += sum_i (beta_i d_i) k_i
// One wave per (b,half). K prefetched 2 blocks ahead, G 1 block ahead.
// ---------------------------------------------------------------------------
__global__ __launch_bounds__(64) void scan_bw8_k(
    const float* __restrict__ proj, const float* __restrict__ g8,
    float* __restrict__ cbuf)
{
    const int pair = blockIdx.x;        // 0..127
    const int b = pair >> 1;
    const int half = pair & 1;
    const int l = threadIdx.x;          // 0..63, owns elems 2l, 2l+1

    const float* kbase = proj + (size_t)b * L_SZ * H_SZ + half * HALF_SZ;
    const float* gbase = g8 + (size_t)pair * 256 * 48;

    // v = q = proj row at token L-1 (token 2047 itself is inert in block 255)
    float2 v = *(const float2*)(kbase + (size_t)(L_SZ - 1) * H_SZ + 2 * l);
    float2 c = make_float2(0.f, 0.f);

    float2 kc[8], kn[8], kf[8];
    float Gc[48], Gf[48];

#pragma unroll
    for (int i = 0; i < 8; ++i) {
        kc[i] = *(const float2*)(kbase + (size_t)(255 * 8 + 7 - i) * H_SZ + 2 * l);
        kn[i] = *(const float2*)(kbase + (size_t)(254 * 8 + 7 - i) * H_SZ + 2 * l);
    }
    {
        const float4* gp = (const float4*)(gbase + (size_t)255 * 48);
#pragma unroll
        for (int i = 0; i < 12; ++i) *(float4*)(Gc + 4 * i) = gp[i];
    }

    for (int bi = 255; bi >= 0; --bi) {
        // prefetch K for block bi-2, G for block bi-1 (clamped; unused tail)
        const int kp = (bi >= 2) ? bi - 2 : 0;
        const int gp_ = (bi >= 1) ? bi - 1 : 0;
#pragma unroll
        for (int i = 0; i < 8; ++i)
            kf[i] = *(const float2*)(kbase + (size_t)(kp * 8 + 7 - i) * H_SZ + 2 * l);
        {
            const float4* gp2 = (const float4*)(gbase + (size_t)gp_ * 48);
#pragma unroll
            for (int i = 0; i < 12; ++i) *(float4*)(Gf + 4 * i) = gp2[i];
        }

        // a-dots (the only cross-lane work per 8 steps)
        float a[8];
#pragma unroll
        for (int i = 0; i < 8; ++i)
            a[i] = kc[i].x * v.x + kc[i].y * v.y;
#pragma unroll
        for (int m = 1; m < 64; m <<= 1)
#pragma unroll
            for (int i = 0; i < 8; ++i)
                a[i] += __shfl_xor(a[i], m);

        // scalar triangular solve with precomputed L (uniform across lanes)
        float d[8];
#pragma unroll
        for (int i = 0; i < 8; ++i) {
            float t = a[i];
            const int off = i * (i - 1) / 2;
#pragma unroll
            for (int j = 0; j < i; ++j)
                t -= Gc[off + j] * d[j];
            d[i] = t;
        }

        float ad[8], bd[8];
#pragma unroll
        for (int i = 0; i < 8; ++i) {
            ad[i] = Gc[28 + i] * d[i];
            bd[i] = Gc[36 + i] * d[i];
        }

        // rank-8 update of v and c
#pragma unroll
        for (int i = 0; i < 8; ++i) {
            v.x = fmaf(-ad[i], kc[i].x, v.x);
            v.y = fmaf(-ad[i], kc[i].y, v.y);
            c.x = fmaf(bd[i], kc[i].x, c.x);
            c.y = fmaf(bd[i], kc[i].y, c.y);
        }

        // rotate pipelines
#pragma unroll
        for (int i = 0; i < 8; ++i) { kc[i] = kn[i]; kn[i] = kf[i]; }
#pragma unroll
        for (int j = 0; j < 48; ++j) Gc[j] = Gf[j];
    }

    *(float2*)(cbuf + b * H_SZ + half * HALF_SZ + 2 * l) = c;
}

// ---------------------------------------------------------------------------
// out[b, v] = sum_h c[b,h] * out_w[h,v] + out_b[v]   (f32 store)
// ---------------------------------------------------------------------------
__global__ __launch_bounds__(256) void out_k(
    const float* __restrict__ c, const float* __restrict__ w,
    const float* __restrict__ ob, float* __restrict__ out)
{
    const int b = blockIdx.x >> 2;
    const int v = ((blockIdx.x & 3) << 8) + threadIdx.x;
    const float* cb = c + b * H_SZ;
    float acc = ob[v];
#pragma unroll 4
    for (int hh = 0; hh < H_SZ; ++hh)
        acc = fmaf(cb[hh], w[(size_t)hh * V_SZ + v], acc);
    out[(size_t)b * V_SZ + v] = acc;
}

// ---------------------------------------------------------------------------
extern "C" void kernel_launch(void* const* d_in, const int* in_sizes, int n_in,
                              void* d_out, int out_size, void* d_ws, size_t ws_size,
                              hipStream_t stream)
{
    const int*   seq   = (const int*)d_in[0];
    const float* embed = (const float*)d_in[1];
    const float* w1    = (const float*)d_in[2];
    const float* b1    = (const float*)d_in[3];
    const float* w2    = (const float*)d_in[4];
    const float* b2    = (const float*)d_in[5];
    const float* ln_g  = (const float*)d_in[6];
    const float* ln_b  = (const float*)d_in[7];
    const float* kp_w  = (const float*)d_in[8];
    const float* kp_b  = (const float*)d_in[9];
    const float* out_w = (const float*)d_in[10];
    const float* out_b = (const float*)d_in[11];

    char* ws = (char*)d_ws;
    size_t off = 0;
    auto alloc = [&](size_t bytes) -> void* {
        void* p = ws + off;
        off += (bytes + 255) & ~(size_t)255;
        return p;
    };

    float*    proj = (float*)alloc((size_t)NTOK * H_SZ * sizeof(float));     // 128 MB
    ushort_t* t1_c = (ushort_t*)alloc((size_t)CH * 512 * sizeof(ushort_t));  // 16 MB
    float*    x_c  = (float*)alloc((size_t)CH * H_SZ * sizeof(float));       // 16 MB
    ushort_t* h_c  = (ushort_t*)alloc((size_t)CH * H_SZ * sizeof(ushort_t)); // 8 MB
    float*    g8   = (float*)alloc((size_t)128 * 256 * 48 * sizeof(float));  // 6.3 MB
    float*    cbuf = (float*)alloc((size_t)B_SZ * H_SZ * sizeof(float));
    // bf16 weight copies
    ushort_t* embed_bf = (ushort_t*)alloc((size_t)V_SZ * H_SZ * 2);          // 512 KB
    ushort_t* w1T = (ushort_t*)alloc((size_t)512 * 256 * 2);                 // 256 KB
    ushort_t* w2T = (ushort_t*)alloc((size_t)256 * 512 * 2);                 // 256 KB
    ushort_t* kpT = (ushort_t*)alloc((size_t)256 * 256 * 2);                 // 128 KB
    float*    outp = (float*)d_out;

    const dim3 blk(256);

    // weight preconversion (bf16 / transposed-bf16)
    cvt_bf16_k<<<dim3((V_SZ * H_SZ) / 1024), blk, 0, stream>>>(
        embed, embed_bf, V_SZ * H_SZ);
    transpose_cvt_k<<<dim3((256 * 512) / 256), blk, 0, stream>>>(w1, w1T, 256, 512);
    transpose_cvt_k<<<dim3((512 * 256) / 256), blk, 0, stream>>>(w2, w2T, 512, 256);
    transpose_cvt_k<<<dim3((256 * 256) / 256), blk, 0, stream>>>(kp_w, kpT, 256, 256);

    for (int c = 0; c < NTOK / CH; ++c) {
        const int base = c * CH;
        const int* seq_c = seq + base;
        // GEMM1: t1 = relu(embed[seq] @ w1 + b1)     M=CH K=256 N=512
        gemm_mfma<1, 256, 512><<<dim3(CH / 128, 4), blk, 0, stream>>>(
            embed_bf, w1T, b1, t1_c, seq_c, nullptr);
        // GEMM2: x = t1 @ w2 + b2 + embed[seq]       M=CH K=512 N=256
        gemm_mfma<2, 512, 256><<<dim3(CH / 128, 2), blk, 0, stream>>>(
            t1_c, w2T, b2, x_c, seq_c, embed);
        // LN: h = LN(x) * g + b  (bf16)
        ln_k<<<dim3(CH / 4), blk, 0, stream>>>(x_c, ln_g, ln_b, h_c);
        // GEMM3: proj = h @ kp_w + kp_b              M=CH K=256 N=256
        gemm_mfma<3, 256, 256><<<dim3(CH / 128, 2), blk, 0, stream>>>(
            h_c, kpT, kp_b, proj + (size_t)base * H_SZ, seq_c, nullptr);
    }

    // parallel precompute of 8x8 block Grams + solve coefficients
    gram8_k<<<dim3(64, 128), blk, 0, stream>>>(proj, g8);
    // serial backward vector scan with precomputed Grams
    scan_bw8_k<<<dim3(128), dim3(64), 0, stream>>>(proj, g8, cbuf);
    out_k<<<dim3(B_SZ * 4), blk, 0, stream>>>(cbuf, out_w, out_b, outp);
}